// Round 4
// baseline (26.421 us; speedup 1.0000x reference)
//
#include <hip/hip_runtime.h>
#include <math.h>

// DETR HungarianMatcher cost matrix on MI355X — round 4.
// C[n,m] = 5*L1 - prob[n,label[m]] - 2*GIoU, [16000 x 1024] f32 out.
// Block = 256 threads, ROWS=16 rows/block, 4 consecutive targets/thread in
// registers. Pred boxes read per-row via UNIFORM global load (s_load path,
// scalar operands) — no LDS row staging, no divergent fill. Row loop
// unrolled 4x only (bounded VGPR pressure). Stores: uniform 64-bit base per
// row + t-scaled offset (SALU addressing).

#define NROWS 16000
#define NC 92
#define M_TGT 1024
#define TPB 256
#define ROWS 16
#define KPT 4   // consecutive targets per thread (KPT*TPB == M_TGT)

__global__ __launch_bounds__(TPB) void hungarian_cost_kernel(
    const float* __restrict__ logits,   // [NROWS, NC]
    const float* __restrict__ pboxes,   // [NROWS, 4] cxcywh
    const float* __restrict__ tboxes,   // [M_TGT, 4] cxcywh
    const int*   __restrict__ tlabels,  // [M_TGT]
    float* __restrict__ out)            // [NROWS, M_TGT]
{
    const int n0 = blockIdx.x * ROWS;
    const int t = threadIdx.x;
    const int lane = t & 63;
    const int wid  = t >> 6;

    __shared__ float negp[ROWS][NC];   // 2 - softmax prob

    // ---- softmax: wave `wid` handles rows 4*wid .. 4*wid+3 ----
    #pragma unroll
    for (int j = 0; j < 4; ++j) {
        const int r = wid * 4 + j;
        const float* lg = logits + (size_t)(n0 + r) * NC;
        const float x0 = lg[lane];                 // lane < 64 < NC
        const bool  hi = (lane < NC - 64);         // lanes 0..27 cover 64..91
        const float x1 = hi ? lg[64 + lane] : -INFINITY;
        float mx = fmaxf(x0, x1);
        #pragma unroll
        for (int off = 32; off >= 1; off >>= 1)
            mx = fmaxf(mx, __shfl_xor(mx, off));
        const float e0 = __expf(x0 - mx);
        const float e1 = hi ? __expf(x1 - mx) : 0.0f;
        float s = e0 + e1;
        #pragma unroll
        for (int off = 32; off >= 1; off >>= 1)
            s += __shfl_xor(s, off);
        const float rs = __builtin_amdgcn_rcpf(s);
        negp[r][lane] = fmaf(-e0, rs, 2.0f);
        if (hi) negp[r][64 + lane] = fmaf(-e1, rs, 2.0f);
    }

    // ---- per-thread target context (registers), m = 4t + k ----
    float tcx[KPT], tcy[KPT], twd[KPT], tht[KPT];
    float bx0[KPT], by0[KPT], bx1[KPT], by1[KPT], areab[KPT];
    const int4 lb4 = reinterpret_cast<const int4*>(tlabels)[t];
    int lbl[KPT] = {lb4.x, lb4.y, lb4.z, lb4.w};
    #pragma unroll
    for (int k = 0; k < KPT; ++k) {
        const float4 tb = reinterpret_cast<const float4*>(tboxes)[4 * t + k];
        tcx[k] = tb.x; tcy[k] = tb.y; twd[k] = tb.z; tht[k] = tb.w;
        bx0[k] = fmaf(-0.5f, tb.z, tb.x);  by0[k] = fmaf(-0.5f, tb.w, tb.y);
        bx1[k] = fmaf( 0.5f, tb.z, tb.x);  by1[k] = fmaf( 0.5f, tb.w, tb.y);
        areab[k] = tb.z * tb.w;
        lbl[k] = (lbl[k] < 0) ? 0 : (lbl[k] > NC - 1 ? NC - 1 : lbl[k]);
    }
    __syncthreads();

    // ---- main: 16 rows x 4 consecutive targets/thread, float4 stores ----
    #pragma unroll 4
    for (int r = 0; r < ROWS; ++r) {
        // uniform address -> scalar load + broadcast; values are wave-uniform
        const float4 pb = reinterpret_cast<const float4*>(pboxes)[n0 + r];
        const float ax0 = fmaf(-0.5f, pb.z, pb.x);
        const float ay0 = fmaf(-0.5f, pb.w, pb.y);
        const float ax1 = fmaf( 0.5f, pb.z, pb.x);
        const float ay1 = fmaf( 0.5f, pb.w, pb.y);
        const float area_a = pb.z * pb.w;
        const float* __restrict__ np = negp[r];

        float tmp[KPT];
        #pragma unroll
        for (int k = 0; k < KPT; ++k) {
            const float cls2 = np[lbl[k]];   // 2 - prob[target class]
            const float cb = fabsf(pb.x - tcx[k]) + fabsf(pb.y - tcy[k])
                           + fabsf(pb.z - twd[k]) + fabsf(pb.w - tht[k]);
            const float iwu = fminf(ax1, bx1[k]) - fmaxf(ax0, bx0[k]);
            const float ihu = fminf(ay1, by1[k]) - fmaxf(ay0, by0[k]);
            const float inter = fmaxf(iwu, 0.0f) * fmaxf(ihu, 0.0f);
            const float uni = area_a + areab[k] - inter;
            const float ew = pb.z + twd[k] - iwu;   // max(a1,b1)-min(a0,b0)
            const float eh = pb.w + tht[k] - ihu;
            const float ae = ew * eh;
            // cost = 5*cb + (2 - cls) - 2*(inter/uni) - 2*(uni/ae)
            const float h = fmaf(inter, __builtin_amdgcn_rcpf(uni),
                                 uni * __builtin_amdgcn_rcpf(ae));
            tmp[k] = fmaf(5.0f, cb, cls2) - 2.0f * h;
        }
        float4 res = {tmp[0], tmp[1], tmp[2], tmp[3]};
        reinterpret_cast<float4*>(out + ((size_t)(n0 + r) << 10))[t] = res;
    }
}

extern "C" void kernel_launch(void* const* d_in, const int* in_sizes, int n_in,
                              void* d_out, int out_size, void* d_ws, size_t ws_size,
                              hipStream_t stream) {
    const float* logits  = (const float*)d_in[0];  // [16,1000,92]
    const float* pboxes  = (const float*)d_in[1];  // [16,1000,4]
    const float* tboxes  = (const float*)d_in[2];  // [1024,4]
    const int*   tlabels = (const int*)d_in[3];    // [1024]
    float* out = (float*)d_out;                    // [16,1000,1024]

    hungarian_cost_kernel<<<NROWS / ROWS, TPB, 0, stream>>>(
        logits, pboxes, tboxes, tlabels, out);
}